// Round 5
// baseline (202.781 us; speedup 1.0000x reference)
//
#include <hip/hip_runtime.h>

#define HW 9216
#define WIDTH 96
#define NCLS 20
#define NOUT 25   // 1 obj + 20 cls + 4 reg
#define CAP 1024
#define NW 16     // CAP/64 mask words per row

// ws layout:
//   [0,256)            cnt[NCLS]
//   [256, 256+160K)    keys[NCLS][CAP] u64
//   [164096, ...)      OVERLAY: partial[8][NOUT][HW] f32 (7.37 MB, dead after
//                      stage2) / mask[NCLS][CAP][NW] u64 (2.56 MB, built after)
#define WS_KEYS   256
#define WS_OVL    164096

// ---------------------------------------------------------------------------
// K1a: GEMM stage 1. Block = 256 threads = 256 positions, ONE 64-channel
// chunk g = blockIdx&7. Channel index is wave-uniform by construction ->
// weights go through the scalar pipe (s_load), no LDS at all. Per-chunk
// k-order (sequential 0..63) and FMA expressions identical to the verified
// monolithic kernel -> bit-exact partial sums.
// ---------------------------------------------------------------------------
__global__ __launch_bounds__(256) void gemm_stage1(
    const float* __restrict__ cls_feat, const float* __restrict__ reg_feat,
    const float* __restrict__ obj_w, const float* __restrict__ cls_w,
    const float* __restrict__ reg_w, float* __restrict__ partial)
{
    const int g   = blockIdx.x & 7;
    const int pos = (blockIdx.x >> 3) * 256 + threadIdx.x;
    const int cb  = g * 64;

    float acc[NOUT];
#pragma unroll
    for (int o = 0; o < NOUT; ++o) acc[o] = 0.f;

    const float* cf = cls_feat + (size_t)cb * HW + pos;
    const float* rf = reg_feat + (size_t)cb * HW + pos;

#pragma unroll 8
    for (int k = 0; k < 64; ++k) {
        const int c = cb + k;                 // uniform -> s_load weights
        float f = cf[(size_t)k * HW];
        float h = rf[(size_t)k * HW];
        acc[0] += f * obj_w[c];
#pragma unroll
        for (int j = 0; j < 20; ++j) acc[1 + j] += f * cls_w[j * 512 + c];
#pragma unroll
        for (int j = 0; j < 4; ++j)  acc[21 + j] += h * reg_w[j * 512 + c];
    }

    float* pg = partial + (size_t)g * NOUT * HW + pos;
#pragma unroll
    for (int o = 0; o < NOUT; ++o) pg[(size_t)o * HW] = acc[o];
}

// ---------------------------------------------------------------------------
// K1b: left-fold the 8 chunk partials in order g=0..7 (same tree as the
// verified kernel's c2=0..7 LDS fold), then the verbatim decode epilogue.
// ---------------------------------------------------------------------------
__global__ __launch_bounds__(256) void decode_stage2(
    const float* __restrict__ partial,
    const float* __restrict__ obj_b, const float* __restrict__ cls_b,
    const float* __restrict__ reg_b,
    float* __restrict__ out, unsigned* __restrict__ cnt,
    unsigned long long* __restrict__ keys)
{
    const int pp = blockIdx.x * 256 + threadIdx.x;

    float d[NOUT];
#pragma unroll
    for (int o = 0; o < NOUT; ++o) {
        float s = 0.f;
#pragma unroll
        for (int g = 0; g < 8; ++g)
            s += partial[((size_t)g * NOUT + o) * HW + pp];
        d[o] = s;
    }

    float obj  = d[0] + obj_b[0];
    float best = d[1] + cls_b[0];
    int   bk   = 0;
#pragma unroll
    for (int k = 1; k < NCLS; ++k) {
        float v = d[1 + k] + cls_b[k];
        if (v > best) { best = v; bk = k; }   // strict > == first-max
    }
    float sobj  = 1.f / (1.f + expf(-obj));
    float scls  = 1.f / (1.f + expf(-best));
    float score = sobj * scls;

    float r0 = d[21] + reg_b[0], r1 = d[22] + reg_b[1];
    float r2 = d[23] + reg_b[2], r3 = d[24] + reg_b[3];
    float gx = (float)(pp % WIDTH), gy = (float)(pp / WIDTH);
    float cx = (1.f / (1.f + expf(-r0)) + gx) * 32.f;
    float cy = (1.f / (1.f + expf(-r1)) + gy) * 32.f;
    float bw = expf(r2) * 32.f;
    float bh = expf(r3) * 32.f;
    float hx = 0.5f * bw, hy = 0.5f * bh;

    ((float4*)out)[pp] = make_float4(cx - hx, cy - hy, cx + hx, cy + hy);
    out[HW * 4 + pp] = score;
    out[HW * 5 + pp] = (float)bk;
    out[HW * 6 + pp] = 0.f;

    if (score >= 0.01f) {
        unsigned slot = atomicAdd(&cnt[bk], 1u);
        if (slot < CAP) {
            unsigned sb = __float_as_uint(score) ^ 0xffffffffu;
            keys[bk * CAP + slot] = ((unsigned long long)sb << 32) | (unsigned)pp;
        }
    }
}

// ---------------------------------------------------------------------------
// K1-fallback: verified monolithic decode (R2-R4, absmax 0). Used only if
// ws_size can't hold the partial buffer.
// ---------------------------------------------------------------------------
__global__ __launch_bounds__(256) void decode_kernel(
    const float* __restrict__ cls_feat, const float* __restrict__ reg_feat,
    const float* __restrict__ obj_w, const float* __restrict__ obj_b,
    const float* __restrict__ cls_w, const float* __restrict__ cls_b,
    const float* __restrict__ reg_w, const float* __restrict__ reg_b,
    float* __restrict__ out, unsigned* __restrict__ cnt,
    unsigned long long* __restrict__ keys)
{
    __shared__ float lds[512 * 28];
    const int tid = threadIdx.x;

    for (int i = tid; i < 25 * 512; i += 256) {
        int o = i >> 9, c = i & 511;
        float v;
        if (o == 0)        v = obj_w[c];
        else if (o < 21)   v = cls_w[(o - 1) * 512 + c];
        else               v = reg_w[(o - 21) * 512 + c];
        lds[c * 28 + o] = v;
    }
    __syncthreads();

    const int posL  = tid & 31;
    const int chunk = tid >> 5;
    const int p     = blockIdx.x * 32 + posL;
    const int cb    = chunk * 64;

    float acc[NOUT];
#pragma unroll
    for (int o = 0; o < NOUT; ++o) acc[o] = 0.f;

    const float* cf = cls_feat + cb * HW + p;
    const float* rf = reg_feat + cb * HW + p;

#pragma unroll 4
    for (int k = 0; k < 64; ++k) {
        float f = cf[k * HW];
        float g = rf[k * HW];
        const float4* w = (const float4*)(lds + (cb + k) * 28);
        float4 w0 = w[0], w1 = w[1], w2 = w[2], w3 = w[3], w4v = w[4], w5 = w[5], w6 = w[6];
        acc[0]  += f * w0.x;  acc[1]  += f * w0.y;  acc[2]  += f * w0.z;  acc[3]  += f * w0.w;
        acc[4]  += f * w1.x;  acc[5]  += f * w1.y;  acc[6]  += f * w1.z;  acc[7]  += f * w1.w;
        acc[8]  += f * w2.x;  acc[9]  += f * w2.y;  acc[10] += f * w2.z;  acc[11] += f * w2.w;
        acc[12] += f * w3.x;  acc[13] += f * w3.y;  acc[14] += f * w3.z;  acc[15] += f * w3.w;
        acc[16] += f * w4v.x; acc[17] += f * w4v.y; acc[18] += f * w4v.z; acc[19] += f * w4v.w;
        acc[20] += f * w5.x;
        acc[21] += g * w5.y;  acc[22] += g * w5.z;  acc[23] += g * w5.w;  acc[24] += g * w6.x;
    }

    __syncthreads();
    float* part = lds;
#pragma unroll
    for (int o = 0; o < NOUT; ++o) part[(chunk * 32 + posL) * NOUT + o] = acc[o];
    __syncthreads();

    float* dots = lds + 8 * 32 * NOUT;
    for (int t = tid; t < 32 * NOUT; t += 256) {
        int pos = t / NOUT, o = t - pos * NOUT;
        float s = 0.f;
#pragma unroll
        for (int c2 = 0; c2 < 8; ++c2) s += part[(c2 * 32 + pos) * NOUT + o];
        dots[t] = s;
    }
    __syncthreads();

    if (tid < 32) {
        const int pos = tid;
        const int pp  = blockIdx.x * 32 + pos;
        const float* d = dots + pos * NOUT;

        float obj  = d[0] + obj_b[0];
        float best = d[1] + cls_b[0];
        int   bk   = 0;
#pragma unroll
        for (int k = 1; k < NCLS; ++k) {
            float v = d[1 + k] + cls_b[k];
            if (v > best) { best = v; bk = k; }
        }
        float sobj  = 1.f / (1.f + expf(-obj));
        float scls  = 1.f / (1.f + expf(-best));
        float score = sobj * scls;

        float r0 = d[21] + reg_b[0], r1 = d[22] + reg_b[1];
        float r2 = d[23] + reg_b[2], r3 = d[24] + reg_b[3];
        float gx = (float)(pp % WIDTH), gy = (float)(pp / WIDTH);
        float cx = (1.f / (1.f + expf(-r0)) + gx) * 32.f;
        float cy = (1.f / (1.f + expf(-r1)) + gy) * 32.f;
        float bw = expf(r2) * 32.f;
        float bh = expf(r3) * 32.f;
        float hx = 0.5f * bw, hy = 0.5f * bh;

        ((float4*)out)[pp] = make_float4(cx - hx, cy - hy, cx + hx, cy + hy);
        out[HW * 4 + pp] = score;
        out[HW * 5 + pp] = (float)bk;
        out[HW * 6 + pp] = 0.f;

        if (score >= 0.01f) {
            unsigned slot = atomicAdd(&cnt[bk], 1u);
            if (slot < CAP) {
                unsigned sb = __float_as_uint(score) ^ 0xffffffffu;
                keys[bk * CAP + slot] = ((unsigned long long)sb << 32) | (unsigned)pp;
            }
        }
    }
}

// ---------------------------------------------------------------------------
// K2: register-resident bitonic sort. 1024 threads x 1 element. Stages with
// j<64 are in-wave shfl_xor (no barrier); only j>=64 (10 stages) touch LDS.
// Keys unique -> deterministic.
// ---------------------------------------------------------------------------
__device__ __forceinline__ unsigned long long shflxor64s(unsigned long long v, int msk) {
    unsigned lo = __shfl_xor((unsigned)v, msk, 64);
    unsigned hi = __shfl_xor((unsigned)(v >> 32), msk, 64);
    return ((unsigned long long)hi << 32) | lo;
}

__global__ __launch_bounds__(1024) void sort_kernel(
    const unsigned* __restrict__ cnt, unsigned long long* __restrict__ keys)
{
    __shared__ unsigned long long a[CAP];
    const int c = blockIdx.x, i = threadIdx.x;
    unsigned m = cnt[c]; if (m > CAP) m = CAP;

    unsigned long long v = (i < (int)m) ? keys[c * CAP + i]
                                        : 0xFFFFFFFFFFFFFFFFull;

    for (int k = 2; k <= CAP; k <<= 1) {
        for (int j = k >> 1; j > 0; j >>= 1) {
            unsigned long long u;
            if (j >= 64) {
                __syncthreads();        // protect previous stage's reads
                a[i] = v;
                __syncthreads();
                u = a[i ^ j];
            } else {
                u = shflxor64s(v, j);
            }
            const bool takeSmall = (((i & k) == 0) == ((i & j) == 0));
            const bool less = v < u;
            v = (takeSmall == less) ? v : u;
        }
    }
    if (i < (int)m) keys[c * CAP + i] = v;
}

// ---------------------------------------------------------------------------
// K3a: parallel mask build (unchanged, verified).
// ---------------------------------------------------------------------------
__global__ __launch_bounds__(1024) void build_kernel(
    const unsigned* __restrict__ cnt, const unsigned long long* __restrict__ keys,
    const float* __restrict__ bboxes, unsigned long long* __restrict__ mask)
{
    __shared__ float4 box[CAP];
    const int c = blockIdx.x >> 4, tile = blockIdx.x & 15;
    const int tid = threadIdx.x, wave = tid >> 6, lane = tid & 63;
    int m = (int)cnt[c]; if (m > CAP) m = CAP;
    const int rbase = tile << 6;
    if (rbase >= m) return;                      // uniform; before any barrier

    if (tid < m) {
        unsigned idx = (unsigned)(keys[c * CAP + tid] & 0xffffffffu);
        box[tid] = ((const float4*)bboxes)[idx];
    } else {
        box[tid] = make_float4(0.f, 0.f, 0.f, 0.f);
    }
    __syncthreads();

    unsigned long long* mrow = mask + (size_t)c * CAP * NW;
#pragma unroll 4
    for (int j = 0; j < 64; ++j) {
        const int row = rbase + (wave << 2) + (j >> 4);   // uniform per wave
        const int w   = j & 15;
        const float4 bi = box[row];
        const float4 bj = box[(w << 6) + lane];
        const float ai = (bi.z - bi.x) * (bi.w - bi.y);
        const float aj = (bj.z - bj.x) * (bj.w - bj.y);
        float iw = fminf(bi.z, bj.z) - fmaxf(bi.x, bj.x);
        float ih = fminf(bi.w, bj.w) - fmaxf(bi.y, bj.y);
        iw = fmaxf(iw, 1e-10f);
        ih = fmaxf(ih, 1e-10f);
        const float inter = iw * ih;
        const float iou = inter / (ai + aj - inter);
        unsigned long long word =
            __ballot((row < m) && (((w << 6) + lane) < m) && (iou > 0.5f));
        if (lane == 0) mrow[row * NW + w] = word;
    }
}

// ---------------------------------------------------------------------------
// K3b: greedy sweep (unchanged, verified fast in R4).
// ---------------------------------------------------------------------------
__device__ __forceinline__ unsigned long long uread64(unsigned long long v, int srclane) {
    unsigned lo = __builtin_amdgcn_readlane((unsigned)v, srclane);
    unsigned hi = __builtin_amdgcn_readlane((unsigned)(v >> 32), srclane);
    return ((unsigned long long)hi << 32) | lo;
}

__global__ __launch_bounds__(64) void sweep_kernel(
    const unsigned* __restrict__ cnt, const unsigned long long* __restrict__ keys,
    const unsigned long long* __restrict__ mask, float* __restrict__ keep)
{
    const int c = blockIdx.x, lane = threadIdx.x;
    int m = (int)cnt[c]; if (m > CAP) m = CAP;
    const int nw = (m + 63) >> 6;
    const unsigned long long* mrow = mask + (size_t)c * CAP * NW;

    const int wsel = lane & 15;
    const int rof  = lane >> 4;

    unsigned long long remw = 0;
    for (int w = 0; w < nw; ++w) {
        const int i0 = w << 6;
        const int nb = min(64, m - i0);

        unsigned long long mykey =
            (lane < nb) ? keys[c * CAP + i0 + lane] : 0ull;
        unsigned long long myrow =
            (lane < nb) ? mrow[(size_t)(i0 + lane) * NW + w] : 0ull;

        unsigned long long rw[16];
#pragma unroll
        for (int j = 0; j < 16; ++j) {
            const int r = i0 + rof + (j << 2);
            rw[j] = (r < m && wsel < nw)
                        ? mrow[(size_t)r * NW + wsel] : 0ull;
        }

        unsigned long long cur  = uread64(remw, w);
        unsigned long long kept = 0;
#pragma unroll
        for (int b = 0; b < 64; ++b) {
            unsigned long long v = uread64(myrow, b);
            unsigned long long alive = ((cur >> b) & 1ull) ^ 1ull;
            kept |= alive << b;
            cur |= v & (0ull - alive);
        }
        if (nb < 64) kept &= (1ull << nb) - 1ull;

        if (lane < nb && ((kept >> lane) & 1ull))
            keep[(unsigned)(mykey & 0xffffffffu)] = 1.0f;

        unsigned long long part = 0;
#pragma unroll
        for (int j = 0; j < 16; ++j) {
            const int b = rof + (j << 2);
            part |= rw[j] & (0ull - ((kept >> b) & 1ull));
        }
        {
            unsigned lo = __shfl_xor((unsigned)part, 16, 64);
            unsigned hi = __shfl_xor((unsigned)(part >> 32), 16, 64);
            part |= ((unsigned long long)hi << 32) | lo;
            lo = __shfl_xor((unsigned)part, 32, 64);
            hi = __shfl_xor((unsigned)(part >> 32), 32, 64);
            part |= ((unsigned long long)hi << 32) | lo;
        }
        if (lane < NW) remw |= part;
    }
}

// ---------------------------------------------------------------------------
extern "C" void kernel_launch(void* const* d_in, const int* in_sizes, int n_in,
                              void* d_out, int out_size, void* d_ws, size_t ws_size,
                              hipStream_t stream)
{
    const float* cls_feat = (const float*)d_in[0];
    const float* reg_feat = (const float*)d_in[1];
    const float* obj_w    = (const float*)d_in[2];
    const float* obj_b    = (const float*)d_in[3];
    const float* cls_w    = (const float*)d_in[4];
    const float* cls_b    = (const float*)d_in[5];
    const float* reg_w    = (const float*)d_in[6];
    const float* reg_b    = (const float*)d_in[7];

    float* out = (float*)d_out;
    unsigned* cnt = (unsigned*)d_ws;
    unsigned long long* keys = (unsigned long long*)((char*)d_ws + WS_KEYS);
    unsigned long long* mask = (unsigned long long*)((char*)d_ws + WS_OVL);
    float* partial           = (float*)((char*)d_ws + WS_OVL);

    hipMemsetAsync(d_ws, 0, 256, stream);   // zero per-class counters

    const size_t need = (size_t)WS_OVL + (size_t)8 * NOUT * HW * sizeof(float);
    if (ws_size >= need) {
        gemm_stage1<<<288, 256, 0, stream>>>(cls_feat, reg_feat,
                                             obj_w, cls_w, reg_w, partial);
        decode_stage2<<<HW / 256, 256, 0, stream>>>(partial, obj_b, cls_b, reg_b,
                                                    out, cnt, keys);
    } else {
        decode_kernel<<<288, 256, 0, stream>>>(cls_feat, reg_feat, obj_w, obj_b,
                                               cls_w, cls_b, reg_w, reg_b,
                                               out, cnt, keys);
    }
    sort_kernel<<<NCLS, 1024, 0, stream>>>(cnt, keys);
    build_kernel<<<NCLS * 16, 1024, 0, stream>>>(cnt, keys, out, mask);
    sweep_kernel<<<NCLS, 64, 0, stream>>>(cnt, keys, mask, out + HW * 6);
}